// Round 3
// baseline (688.098 us; speedup 1.0000x reference)
//
#include <hip/hip_runtime.h>
#include <math.h>

#define DEV __device__ __forceinline__

struct F3 { float x, y, z; };
DEV F3 f3(float x, float y, float z) { F3 r; r.x = x; r.y = y; r.z = z; return r; }
DEV F3 sub3(F3 a, F3 b) { return f3(a.x - b.x, a.y - b.y, a.z - b.z); }
DEV F3 add3(F3 a, F3 b) { return f3(a.x + b.x, a.y + b.y, a.z + b.z); }
DEV F3 scl3(F3 a, float s) { return f3(a.x * s, a.y * s, a.z * s); }
DEV float dot3(F3 a, F3 b) { return a.x * b.x + a.y * b.y + a.z * b.z; }

#define EXCL_EPS 2.0f
#define PIF 3.14159265358979323846f
#define HPIF 1.57079632679489661923f

DEV float mimg1(float d, float box, float ibox) { return d - box * rintf(d * ibox); }
DEV F3 mimg(F3 d, F3 box, F3 ibox) {
    return f3(mimg1(d.x, box.x, ibox.x), mimg1(d.y, box.y, ibox.y), mimg1(d.z, box.z, ibox.z));
}
DEV float norm3(F3 d) { return sqrtf(dot3(d, d) + 1e-12f); }

DEV float acosc(float c) {
    c = fminf(fmaxf(c, -1.0f + 1e-6f), 1.0f - 1e-6f);
    return acosf(c);
}

// EXACT Round-1 exclusion (proven bit-compatible with reference on dominant pairs)
DEV float fexcl(float r, float sigma, float rstar, float b, float rc) {
    float res = 0.0f;
    if (r < rc) {
        if (r < rstar) {
            float s = sigma / r;
            float s2 = s * s;
            float s6 = s2 * s2 * s2;
            res = 4.0f * EXCL_EPS * (s6 * s6 - s6);
        } else {
            float d = r - rc;
            res = EXCL_EPS * b * d * d;
        }
    }
    return res;
}

DEV float f1f(float r, float a, float r0, float shift, float rlow, float rhigh,
              float blow, float rclow, float bhigh, float rchigh) {
    float res = 0.0f;
    if (r > rlow && r < rhigh) {
        float t = __expf(-a * (r - r0)) - 1.0f;
        res = t * t - shift;
    } else if (r > rclow && r <= rlow) {
        float d = r - rclow; res = blow * d * d;
    } else if (r >= rhigh && r < rchigh) {
        float d = r - rchigh; res = bhigh * d * d;
    }
    return res;
}

DEV float f2f(float r, float k, float r0, float rc, float rlow, float rhigh,
              float blow, float rclow, float bhigh, float rchigh) {
    float res = 0.0f;
    if (r > rlow && r < rhigh) {
        float d = r - r0, dc = rc - r0;
        res = 0.5f * k * (d * d - dc * dc);
    } else if (r > rclow && r <= rlow) {
        float d = r - rclow; res = k * blow * d * d;
    } else if (r >= rhigh && r < rchigh) {
        float d = r - rchigh; res = k * bhigh * d * d;
    }
    return res;
}

DEV float f4f(float th, float a, float t0, float ts, float b, float tc) {
    float dt = fabsf(th - t0);
    float res = 0.0f;
    if (dt < ts) res = 1.0f - a * dt * dt;
    else if (dt < tc) { float d = tc - dt; res = b * d * d; }
    return res;
}

DEV float f5f(float x, float a, float xs, float b, float xc) {
    float res = 0.0f;
    if (x > 0.0f) res = 1.0f;
    else if (x > xs) res = 1.0f - a * x * x;
    else if (x > xc) { float d = xc - x; res = b * d * d; }
    return res;
}

// block = 256 threads = 4 waves; double reduce, atomic to one of 64 slots
DEV void block_reduce_atomic(float e, double* __restrict__ slots) {
    double v = (double)e;
#pragma unroll
    for (int off = 32; off > 0; off >>= 1) v += __shfl_down(v, off, 64);
    __shared__ double red[4];
    int lane = threadIdx.x & 63;
    int wv = threadIdx.x >> 6;
    if (lane == 0) red[wv] = v;
    __syncthreads();
    if (threadIdx.x == 0) {
        double s = red[0] + red[1] + red[2] + red[3];
        atomicAdd(slots + (blockIdx.x & 63), s);
    }
}

// EXACT Round-1 frame/site computation (proven absmax 0.0)
DEV void load_particle(const float* __restrict__ pos, const float4* __restrict__ quat, int i,
                       F3& a1, F3& a2, F3& a3, F3& back, F3& stck, F3& base) {
    float4 q = quat[i];
    float n = sqrtf(q.x * q.x + q.y * q.y + q.z * q.z + q.w * q.w + 1e-12f);
    float inv = 1.0f / n;
    float w = q.x * inv, x = q.y * inv, y = q.z * inv, z = q.w * inv;
    a1 = f3(1.0f - 2.0f * (y * y + z * z), 2.0f * (x * y + w * z), 2.0f * (x * z - w * y));
    a2 = f3(2.0f * (x * y - w * z), 1.0f - 2.0f * (x * x + z * z), 2.0f * (y * z + w * x));
    a3 = f3(2.0f * (x * z + w * y), 2.0f * (y * z - w * x), 1.0f - 2.0f * (x * x + y * y));
    F3 p = f3(pos[3 * i], pos[3 * i + 1], pos[3 * i + 2]);
    back = add3(p, scl3(a1, -0.4f));
    stck = add3(p, scl3(a1, 0.34f));
    base = add3(p, scl3(a1, 0.4f));
}

// ---------------------------------------------------------------------------
// packed records: recS = 64 B/particle (one cache line):
//   s0 = (back.x, back.y, back.z, stck.x)
//   s1 = (stck.y, stck.z, base.x, base.y)
//   s2 = (base.z, a1.x,  a1.y,  a1.z)
//   s3 = (a2.x,  a2.y,  a2.z,  btype)
// recB = 16 B/particle: (a3.x, a3.y, a3.z, 0)  -- heavy phase + bonded only
// ---------------------------------------------------------------------------

__global__ void __launch_bounds__(256)
prep_kernel(const float* __restrict__ pos, const float4* __restrict__ quat,
            const int* __restrict__ btypes, int n,
            float4* __restrict__ recS, float4* __restrict__ recB) {
    int i = blockIdx.x * blockDim.x + threadIdx.x;
    if (i >= n) return;
    F3 a1, a2, a3, back, stck, base;
    load_particle(pos, quat, i, a1, a2, a3, back, stck, base);
    recS[4 * i + 0] = make_float4(back.x, back.y, back.z, stck.x);
    recS[4 * i + 1] = make_float4(stck.y, stck.z, base.x, base.y);
    recS[4 * i + 2] = make_float4(base.z, a1.x, a1.y, a1.z);
    recS[4 * i + 3] = make_float4(a2.x, a2.y, a2.z, __int_as_float(btypes[i]));
    recB[i] = make_float4(a3.x, a3.y, a3.z, 0.0f);
}

struct Sites { F3 back, stck, base; };
DEV Sites unpack_sites(float4 s0, float4 s1, float4 s2) {
    Sites s;
    s.back = f3(s0.x, s0.y, s0.z);
    s.stck = f3(s0.w, s1.x, s1.y);
    s.base = f3(s1.z, s1.w, s2.x);
    return s;
}

// Phase A: exclusions for all nonbonded pairs + compact active pairs.
// K=2 pairs per thread, gathers staged up front.
__global__ void __launch_bounds__(256)
phaseA_kernel(const float4* __restrict__ recS, const int2* __restrict__ pairs,
              int n, const float* __restrict__ boxp, double* __restrict__ slots,
              unsigned* __restrict__ counter, int2* __restrict__ list, unsigned cap) {
    const int T = gridDim.x * blockDim.x;
    const int t = blockIdx.x * blockDim.x + threadIdx.x;
    float bx = boxp[0], by = boxp[1], bz = boxp[2];
    F3 box = f3(bx, by, bz);
    F3 ibox = f3(1.0f / bx, 1.0f / by, 1.0f / bz);

    int2 pr[2];
    bool v[2];
    float4 si0[2], si1[2], si2[2], sj0[2], sj1[2], sj2[2];
#pragma unroll
    for (int k = 0; k < 2; k++) {
        int idx = t + k * T;
        v[k] = idx < n;
        pr[k] = v[k] ? pairs[idx] : make_int2(0, 0);
    }
#pragma unroll
    for (int k = 0; k < 2; k++) {
        const float4* ri = recS + 4 * (size_t)pr[k].x;
        const float4* rj = recS + 4 * (size_t)pr[k].y;
        si0[k] = ri[0]; si1[k] = ri[1]; si2[k] = ri[2];
        sj0[k] = rj[0]; sj1[k] = rj[1]; sj2[k] = rj[2];
    }

    float e = 0.0f;
    int lane = threadIdx.x & 63;
#pragma unroll
    for (int k = 0; k < 2; k++) {
        Sites si = unpack_sites(si0[k], si1[k], si2[k]);
        Sites sj = unpack_sites(sj0[k], sj1[k], sj2[k]);

        F3 dbb = mimg(sub3(sj.back, si.back), box, ibox);
        F3 dba = mimg(sub3(sj.base, si.base), box, ibox);
        F3 dm1 = mimg(sub3(sj.base, si.back), box, ibox);  // base_j - back_i
        F3 dm2 = mimg(sub3(sj.back, si.base), box, ibox);  // back_j - base_i
        F3 dst = mimg(sub3(sj.stck, si.stck), box, ibox);

        float rrbb = dot3(dbb, dbb) + 1e-12f;
        float rrb  = dot3(dba, dba) + 1e-12f;
        float rr1  = dot3(dm1, dm1) + 1e-12f;
        float rr2  = dot3(dm2, dm2) + 1e-12f;
        float rrs  = dot3(dst, dst) + 1e-12f;

        float ek = 0.0f;
        // EXCL_BB
        if (rrbb < 0.711879214356f * 0.711879214356f)
            ek += fexcl(sqrtf(rrbb), 0.7f, 0.675f, 892.016223343f, 0.711879214356f);
        // EXCL_BASE
        if (rrb < 0.335388426126f * 0.335388426126f)
            ek += fexcl(sqrtf(rrb), 0.33f, 0.32f, 4119.70450017f, 0.335388426126f);
        // EXCL_MIX x2
        if (rr1 < 0.52329943261f * 0.52329943261f)
            ek += fexcl(sqrtf(rr1), 0.515f, 0.5f, 2047.42812499f, 0.52329943261f);
        if (rr2 < 0.52329943261f * 0.52329943261f)
            ek += fexcl(sqrtf(rr2), 0.515f, 0.5f, 2047.42812499f, 0.52329943261f);
        e += v[k] ? ek : 0.0f;

        // active iff hb/crst radial support (rb in (0.276,0.783)) or cxst (rcx in (0.2,0.62))
        bool active = v[k] && ((rrb > 0.276f * 0.276f && rrb < 0.783f * 0.783f) ||
                               (rrs > 0.2f * 0.2f && rrs < 0.62f * 0.62f));
        unsigned long long mask = __ballot(active);
        if (active) {
            unsigned long long lt = mask & ((1ull << lane) - 1ull);
            unsigned base = 0;
            if (lt == 0ull) base = atomicAdd(counter, (unsigned)__popcll(mask));
            base = (unsigned)__builtin_amdgcn_readfirstlane((int)base);
            unsigned slot = base + (unsigned)__popcll(lt);
            if (slot < cap) list[slot] = pr[k];
        }
    }
    block_reduce_atomic(e, slots);
}

// Phase B: heavy angular math (hb + crst + cxst) on compacted pairs.
__global__ void __launch_bounds__(256)
phaseB_kernel(const float4* __restrict__ recS, const float4* __restrict__ recB,
              const float* __restrict__ hbe, const float* __restrict__ boxp,
              const int2* __restrict__ list, const unsigned* __restrict__ counter,
              unsigned cap, double* __restrict__ slots) {
    unsigned count = *counter;
    if (count > cap) count = cap;
    float bx = boxp[0], by = boxp[1], bz = boxp[2];
    F3 box = f3(bx, by, bz);
    F3 ibox = f3(1.0f / bx, 1.0f / by, 1.0f / bz);
    const unsigned T = gridDim.x * blockDim.x;
    float e = 0.0f;
    for (unsigned idx = blockIdx.x * blockDim.x + threadIdx.x; idx < count; idx += T) {
        int2 p = list[idx];
        int i = p.x, j = p.y;
        float4 i0 = recS[4 * (size_t)i], i1 = recS[4 * (size_t)i + 1],
               i2 = recS[4 * (size_t)i + 2], i3 = recS[4 * (size_t)i + 3];
        float4 j0 = recS[4 * (size_t)j], j1 = recS[4 * (size_t)j + 1],
               j2 = recS[4 * (size_t)j + 2], j3 = recS[4 * (size_t)j + 3];
        float4 b3i = recB[i], b3j = recB[j];
        Sites si = unpack_sites(i0, i1, i2);
        Sites sj = unpack_sites(j0, j1, j2);
        F3 a1i = f3(i2.y, i2.z, i2.w), a1j = f3(j2.y, j2.z, j2.w);
        F3 a2i = f3(i3.x, i3.y, i3.z), a2j = f3(j3.x, j3.y, j3.z);
        F3 a3i = f3(b3i.x, b3i.y, b3i.z), a3j = f3(b3j.x, b3j.y, b3j.z);
        int bti = __float_as_int(i3.w), btj = __float_as_int(j3.w);

        F3 dbase = mimg(sub3(sj.base, si.base), box, ibox);
        float rb = norm3(dbase);
        F3 rhat = scl3(dbase, 1.0f / rb);

        float t1  = acosc(-dot3(a1i, a1j));
        float t2  = acosc(-dot3(a1j, rhat));
        float t3  = acosc(dot3(a1i, rhat));
        float t4h = acosc(dot3(a3i, a3j));
        float t7  = acosc(-dot3(a3j, rhat));
        float t8  = acosc(dot3(a3i, rhat));

        float eps = hbe[bti * 4 + btj];
        float f4t7 = f4f(t7, 4.0f, HPIF, 0.45f, 17.0526f, 0.555556f);
        e += eps
           * f1f(rb, 8.0f, 0.4f, 0.88207774f, 0.34f, 0.7f, -126.2f, 0.276f, -7.87f, 0.783f)
           * f4f(t1, 1.5f, 0.0f, 0.7f, 4.16038f, 0.952381f)
           * f4f(t2, 1.5f, 0.0f, 0.7f, 4.16038f, 0.952381f)
           * f4f(t3, 1.5f, 0.0f, 0.7f, 4.16038f, 0.952381f)
           * f4f(t4h, 0.46f, PIF, 0.7f, 1.14813f, 3.0f)
           * f4t7
           * f4f(t8, 4.0f, HPIF, 0.45f, 17.0526f, 0.555556f);

        e += f2f(rb, 47.5f, 0.575f, 0.675f, 0.495f, 0.655f, -0.888f, 0.45f, -0.888f, 0.68f)
           * f4f(t1, 2.25f, 0.791592653589793f, 0.58f, 10.9032f, 0.766284f)
           * f4f(t4h, 1.5f, 0.0f, 0.7f, 4.16038f, 0.952381f)
           * (f4t7 + f4f(PIF - t7, 4.0f, HPIF, 0.45f, 17.0526f, 0.555556f));

        F3 dc = mimg(sub3(sj.stck, si.stck), box, ibox);
        float rcx = norm3(dc);
        F3 rchat = scl3(dc, 1.0f / rcx);
        float ct5 = acosc(dot3(a3j, rchat));
        float cphi3 = dot3(a2i, a2j);
        e += f2f(rcx, 46.0f, 0.4f, 0.6f, 0.22f, 0.58f, -0.7f, 0.2f, -0.7f, 0.62f)
           * f4f(t1, 2.0f, 2.592f, 0.65f, 10.9032f, 0.766284f)
           * f4f(t4h, 1.3f, 0.0f, 0.8f, 6.4f, 0.961538f)
           * f4f(ct5, 0.9f, 0.0f, 0.95f, 3.9f, 1.16959f)
           * f5f(cphi3, 2.0f, -0.65f, 10.9032f, -0.769231f);
    }
    block_reduce_atomic(e, slots);
}

// bonded from packed records (sites are exact reference fp32 values)
__global__ void __launch_bounds__(256)
bonded_packed_kernel(const float4* __restrict__ recS, const float4* __restrict__ recB,
                     const float* __restrict__ seps, const float* __restrict__ boxp,
                     const int2* __restrict__ pairs, int n, double* __restrict__ slots) {
    int t = blockIdx.x * blockDim.x + threadIdx.x;
    float e = 0.0f;
    if (t < n) {
        float bx = boxp[0], by = boxp[1], bz = boxp[2];
        F3 box = f3(bx, by, bz);
        F3 ibox = f3(1.0f / bx, 1.0f / by, 1.0f / bz);
        int2 p = pairs[t];
        int i = p.x, j = p.y;
        float4 i0 = recS[4 * (size_t)i], i1 = recS[4 * (size_t)i + 1],
               i2 = recS[4 * (size_t)i + 2], i3 = recS[4 * (size_t)i + 3];
        float4 j0 = recS[4 * (size_t)j], j1 = recS[4 * (size_t)j + 1],
               j2 = recS[4 * (size_t)j + 2], j3 = recS[4 * (size_t)j + 3];
        float4 b3i = recB[i], b3j = recB[j];
        Sites si = unpack_sites(i0, i1, i2);
        Sites sj = unpack_sites(j0, j1, j2);
        F3 a2i = f3(i3.x, i3.y, i3.z), a2j = f3(j3.x, j3.y, j3.z);
        F3 a3i = f3(b3i.x, b3i.y, b3i.z), a3j = f3(b3j.x, b3j.y, b3j.z);

        // FENE
        F3 dbb = mimg(sub3(sj.back, si.back), box, ibox);
        float rbb = norm3(dbb);
        float u = (rbb - 0.7525f) * 4.0f;
        float arg = u * u;
        arg = fminf(fmaxf(arg, 0.0f), 1.0f - 1e-6f);
        e += -log1pf(-arg);  // -0.5 * FENE_EPS(2) * log1p

        // bonded exclusions (base-base, basej-backi, backj-basei)
        e += fexcl(norm3(mimg(sub3(sj.base, si.base), box, ibox)), 0.33f, 0.32f, 4119.70450017f, 0.335388426126f);
        e += fexcl(norm3(mimg(sub3(sj.base, si.back), box, ibox)), 0.515f, 0.5f, 2047.42812499f, 0.52329943261f);
        e += fexcl(norm3(mimg(sub3(sj.back, si.base), box, ibox)), 0.515f, 0.5f, 2047.42812499f, 0.52329943261f);

        // stacking
        F3 ds = mimg(sub3(sj.stck, si.stck), box, ibox);
        float rs = norm3(ds);
        F3 rhat = scl3(ds, 1.0f / rs);
        float t4 = acosc(dot3(a3i, a3j));
        float t5 = acosc(dot3(a3j, rhat));
        float t6 = acosc(-dot3(a3i, rhat));
        F3 rbhat = scl3(dbb, 1.0f / rbb);
        float cphi1 = dot3(a2i, rbhat);
        float cphi2 = dot3(a2j, rbhat);
        e += seps[t]
           * f1f(rs, 6.0f, 0.4f, 0.90290461f, 0.32f, 0.75f, -0.68f, 0.26f, -12.6f, 0.8f)
           * f4f(t4, 1.3f, 0.0f, 0.8f, 6.4f, 0.961538f)
           * f4f(t5, 0.9f, 0.0f, 0.95f, 3.9f, 1.16959f)
           * f4f(t6, 0.9f, 0.0f, 0.95f, 3.9f, 1.16959f)
           * f5f(cphi1, 2.0f, -0.65f, 10.9032f, -0.769231f)
           * f5f(cphi2, 2.0f, -0.65f, 10.9032f, -0.769231f);
    }
    block_reduce_atomic(e, slots);
}

__global__ void finalize_kernel(const double* __restrict__ slots, float* __restrict__ out) {
    double v = slots[threadIdx.x];
#pragma unroll
    for (int off = 32; off > 0; off >>= 1) v += __shfl_down(v, off, 64);
    if (threadIdx.x == 0) out[0] = (float)v;
}

// ---------------------------------------------------------------------------
// mono fallback (Round-1 proven path), used only if ws_size too small
// ---------------------------------------------------------------------------

__global__ void __launch_bounds__(256)
mono_bonded_kernel(const float* __restrict__ pos, const float4* __restrict__ quat,
                   const float* __restrict__ seps, const float* __restrict__ boxp,
                   const int2* __restrict__ pairs, int n, double* __restrict__ slots) {
    int t = blockIdx.x * blockDim.x + threadIdx.x;
    float e = 0.0f;
    if (t < n) {
        float bx = boxp[0], by = boxp[1], bz = boxp[2];
        F3 box = f3(bx, by, bz);
        F3 ibox = f3(1.0f / bx, 1.0f / by, 1.0f / bz);
        int2 p = pairs[t];
        int i = p.x, j = p.y;
        F3 a1i, a2i, a3i, backi, stcki, basei;
        F3 a1j, a2j, a3j, backj, stckj, basej;
        load_particle(pos, quat, i, a1i, a2i, a3i, backi, stcki, basei);
        load_particle(pos, quat, j, a1j, a2j, a3j, backj, stckj, basej);
        F3 dbb = mimg(sub3(backj, backi), box, ibox);
        float rbb = norm3(dbb);
        float u = (rbb - 0.7525f) * 4.0f;
        float arg = u * u;
        arg = fminf(fmaxf(arg, 0.0f), 1.0f - 1e-6f);
        e += -log1pf(-arg);
        e += fexcl(norm3(mimg(sub3(basej, basei), box, ibox)), 0.33f, 0.32f, 4119.70450017f, 0.335388426126f);
        e += fexcl(norm3(mimg(sub3(basej, backi), box, ibox)), 0.515f, 0.5f, 2047.42812499f, 0.52329943261f);
        e += fexcl(norm3(mimg(sub3(backj, basei), box, ibox)), 0.515f, 0.5f, 2047.42812499f, 0.52329943261f);
        F3 ds = mimg(sub3(stckj, stcki), box, ibox);
        float rs = norm3(ds);
        F3 rhat = scl3(ds, 1.0f / rs);
        float t4 = acosc(dot3(a3i, a3j));
        float t5 = acosc(dot3(a3j, rhat));
        float t6 = acosc(-dot3(a3i, rhat));
        F3 rbhat = scl3(dbb, 1.0f / rbb);
        float cphi1 = dot3(a2i, rbhat);
        float cphi2 = dot3(a2j, rbhat);
        e += seps[t]
           * f1f(rs, 6.0f, 0.4f, 0.90290461f, 0.32f, 0.75f, -0.68f, 0.26f, -12.6f, 0.8f)
           * f4f(t4, 1.3f, 0.0f, 0.8f, 6.4f, 0.961538f)
           * f4f(t5, 0.9f, 0.0f, 0.95f, 3.9f, 1.16959f)
           * f4f(t6, 0.9f, 0.0f, 0.95f, 3.9f, 1.16959f)
           * f5f(cphi1, 2.0f, -0.65f, 10.9032f, -0.769231f)
           * f5f(cphi2, 2.0f, -0.65f, 10.9032f, -0.769231f);
    }
    block_reduce_atomic(e, slots);
}

__global__ void __launch_bounds__(256)
mono_nonbonded_kernel(const float* __restrict__ pos, const float4* __restrict__ quat,
                      const float* __restrict__ hbe, const float* __restrict__ boxp,
                      const int2* __restrict__ pairs, const int* __restrict__ btypes,
                      int n, double* __restrict__ slots) {
    int t = blockIdx.x * blockDim.x + threadIdx.x;
    float e = 0.0f;
    if (t < n) {
        float bx = boxp[0], by = boxp[1], bz = boxp[2];
        F3 box = f3(bx, by, bz);
        F3 ibox = f3(1.0f / bx, 1.0f / by, 1.0f / bz);
        int2 p = pairs[t];
        int i = p.x, j = p.y;
        F3 a1i, a2i, a3i, backi, stcki, basei;
        F3 a1j, a2j, a3j, backj, stckj, basej;
        load_particle(pos, quat, i, a1i, a2i, a3i, backi, stcki, basei);
        load_particle(pos, quat, j, a1j, a2j, a3j, backj, stckj, basej);
        e += fexcl(norm3(mimg(sub3(backj, backi), box, ibox)), 0.7f, 0.675f, 892.016223343f, 0.711879214356f);
        F3 dbase = mimg(sub3(basej, basei), box, ibox);
        float rb = norm3(dbase);
        e += fexcl(rb, 0.33f, 0.32f, 4119.70450017f, 0.335388426126f);
        e += fexcl(norm3(mimg(sub3(basej, backi), box, ibox)), 0.515f, 0.5f, 2047.42812499f, 0.52329943261f);
        e += fexcl(norm3(mimg(sub3(backj, basei), box, ibox)), 0.515f, 0.5f, 2047.42812499f, 0.52329943261f);
        F3 rhat = scl3(dbase, 1.0f / rb);
        float t1  = acosc(-dot3(a1i, a1j));
        float t2  = acosc(-dot3(a1j, rhat));
        float t3  = acosc(dot3(a1i, rhat));
        float t4h = acosc(dot3(a3i, a3j));
        float t7  = acosc(-dot3(a3j, rhat));
        float t8  = acosc(dot3(a3i, rhat));
        int bti = btypes[i], btj = btypes[j];
        float eps = hbe[bti * 4 + btj];
        float f4t7 = f4f(t7, 4.0f, HPIF, 0.45f, 17.0526f, 0.555556f);
        e += eps
           * f1f(rb, 8.0f, 0.4f, 0.88207774f, 0.34f, 0.7f, -126.2f, 0.276f, -7.87f, 0.783f)
           * f4f(t1, 1.5f, 0.0f, 0.7f, 4.16038f, 0.952381f)
           * f4f(t2, 1.5f, 0.0f, 0.7f, 4.16038f, 0.952381f)
           * f4f(t3, 1.5f, 0.0f, 0.7f, 4.16038f, 0.952381f)
           * f4f(t4h, 0.46f, PIF, 0.7f, 1.14813f, 3.0f)
           * f4t7
           * f4f(t8, 4.0f, HPIF, 0.45f, 17.0526f, 0.555556f);
        e += f2f(rb, 47.5f, 0.575f, 0.675f, 0.495f, 0.655f, -0.888f, 0.45f, -0.888f, 0.68f)
           * f4f(t1, 2.25f, 0.791592653589793f, 0.58f, 10.9032f, 0.766284f)
           * f4f(t4h, 1.5f, 0.0f, 0.7f, 4.16038f, 0.952381f)
           * (f4t7 + f4f(PIF - t7, 4.0f, HPIF, 0.45f, 17.0526f, 0.555556f));
        F3 dc = mimg(sub3(stckj, stcki), box, ibox);
        float rcx = norm3(dc);
        F3 rchat = scl3(dc, 1.0f / rcx);
        float ct5 = acosc(dot3(a3j, rchat));
        float cphi3 = dot3(a2i, a2j);
        e += f2f(rcx, 46.0f, 0.4f, 0.6f, 0.22f, 0.58f, -0.7f, 0.2f, -0.7f, 0.62f)
           * f4f(t1, 2.0f, 2.592f, 0.65f, 10.9032f, 0.766284f)
           * f4f(t4h, 1.3f, 0.0f, 0.8f, 6.4f, 0.961538f)
           * f4f(ct5, 0.9f, 0.0f, 0.95f, 3.9f, 1.16959f)
           * f5f(cphi3, 2.0f, -0.65f, 10.9032f, -0.769231f);
    }
    block_reduce_atomic(e, slots);
}

extern "C" void kernel_launch(void* const* d_in, const int* in_sizes, int n_in,
                              void* d_out, int out_size, void* d_ws, size_t ws_size,
                              hipStream_t stream) {
    const float*  pos  = (const float*)d_in[0];
    const float4* quat = (const float4*)d_in[1];
    const float*  seps = (const float*)d_in[2];
    const float*  hbe  = (const float*)d_in[3];
    const float*  boxp = (const float*)d_in[4];
    const int2*   bp   = (const int2*)d_in[5];
    const int2*   nbp  = (const int2*)d_in[6];
    const int*    bt   = (const int*)d_in[7];

    int N    = in_sizes[0] / 3;
    int n_b  = in_sizes[5] / 2;
    int n_nb = in_sizes[6] / 2;

    char* ws = (char*)d_ws;
    // layout: [0,64) counter, [64,576) slots, [1024,..) recS (64B/p), recB (16B/p), list
    size_t off_recS = 1024;
    size_t off_recB = off_recS + (size_t)N * 64;
    size_t off_list = off_recB + (size_t)N * 16;
    size_t required = off_list + (size_t)n_nb * 8;

    if (ws_size >= required) {
        unsigned* counter = (unsigned*)ws;
        double*   slots   = (double*)(ws + 64);
        float4*   recS    = (float4*)(ws + off_recS);
        float4*   recB    = (float4*)(ws + off_recB);
        int2*     list    = (int2*)(ws + off_list);
        hipMemsetAsync(ws, 0, 576, stream);
        prep_kernel<<<(N + 255) / 256, 256, 0, stream>>>(pos, quat, bt, N, recS, recB);
        bonded_packed_kernel<<<(n_b + 255) / 256, 256, 0, stream>>>(recS, recB, seps, boxp, bp, n_b, slots);
        int pa_threads = (n_nb + 1) / 2;
        int pa_blocks = (pa_threads + 255) / 256;
        phaseA_kernel<<<pa_blocks, 256, 0, stream>>>(recS, nbp, n_nb, boxp, slots, counter, list, (unsigned)n_nb);
        phaseB_kernel<<<512, 256, 0, stream>>>(recS, recB, hbe, boxp, list, counter, (unsigned)n_nb, slots);
        finalize_kernel<<<1, 64, 0, stream>>>(slots, (float*)d_out);
    } else {
        double* slots = (double*)ws;
        hipMemsetAsync(ws, 0, 512, stream);
        mono_bonded_kernel<<<(n_b + 255) / 256, 256, 0, stream>>>(pos, quat, seps, boxp, bp, n_b, slots);
        mono_nonbonded_kernel<<<(n_nb + 255) / 256, 256, 0, stream>>>(pos, quat, hbe, boxp, nbp, bt, n_nb, slots);
        finalize_kernel<<<1, 64, 0, stream>>>(slots, (float*)d_out);
    }
}

// Round 4
// 229.333 us; speedup vs baseline: 3.0004x; 3.0004x over previous
//
#include <hip/hip_runtime.h>
#include <math.h>

#define DEV __device__ __forceinline__

struct F3 { float x, y, z; };
DEV F3 f3(float x, float y, float z) { F3 r; r.x = x; r.y = y; r.z = z; return r; }
DEV F3 sub3(F3 a, F3 b) { return f3(a.x - b.x, a.y - b.y, a.z - b.z); }
DEV F3 add3(F3 a, F3 b) { return f3(a.x + b.x, a.y + b.y, a.z + b.z); }
DEV F3 scl3(F3 a, float s) { return f3(a.x * s, a.y * s, a.z * s); }
DEV float dot3(F3 a, F3 b) { return a.x * b.x + a.y * b.y + a.z * b.z; }

#define EXCL_EPS 2.0f
#define PIF 3.14159265358979323846f
#define HPIF 1.57079632679489661923f

DEV float mimg1(float d, float box, float ibox) { return d - box * rintf(d * ibox); }
DEV F3 mimg(F3 d, F3 box, F3 ibox) {
    return f3(mimg1(d.x, box.x, ibox.x), mimg1(d.y, box.y, ibox.y), mimg1(d.z, box.z, ibox.z));
}
DEV float norm3(F3 d) { return sqrtf(dot3(d, d) + 1e-12f); }

DEV float acosc(float c) {
    c = fminf(fmaxf(c, -1.0f + 1e-6f), 1.0f - 1e-6f);
    return acosf(c);
}

// EXACT Round-1 exclusion (bit-compatible with reference on dominant pairs)
DEV float fexcl(float r, float sigma, float rstar, float b, float rc) {
    float res = 0.0f;
    if (r < rc) {
        if (r < rstar) {
            float s = sigma / r;
            float s2 = s * s;
            float s6 = s2 * s2 * s2;
            res = 4.0f * EXCL_EPS * (s6 * s6 - s6);
        } else {
            float d = r - rc;
            res = EXCL_EPS * b * d * d;
        }
    }
    return res;
}

DEV float f1f(float r, float a, float r0, float shift, float rlow, float rhigh,
              float blow, float rclow, float bhigh, float rchigh) {
    float res = 0.0f;
    if (r > rlow && r < rhigh) {
        float t = __expf(-a * (r - r0)) - 1.0f;
        res = t * t - shift;
    } else if (r > rclow && r <= rlow) {
        float d = r - rclow; res = blow * d * d;
    } else if (r >= rhigh && r < rchigh) {
        float d = r - rchigh; res = bhigh * d * d;
    }
    return res;
}

DEV float f2f(float r, float k, float r0, float rc, float rlow, float rhigh,
              float blow, float rclow, float bhigh, float rchigh) {
    float res = 0.0f;
    if (r > rlow && r < rhigh) {
        float d = r - r0, dc = rc - r0;
        res = 0.5f * k * (d * d - dc * dc);
    } else if (r > rclow && r <= rlow) {
        float d = r - rclow; res = k * blow * d * d;
    } else if (r >= rhigh && r < rchigh) {
        float d = r - rchigh; res = k * bhigh * d * d;
    }
    return res;
}

DEV float f4f(float th, float a, float t0, float ts, float b, float tc) {
    float dt = fabsf(th - t0);
    float res = 0.0f;
    if (dt < ts) res = 1.0f - a * dt * dt;
    else if (dt < tc) { float d = tc - dt; res = b * d * d; }
    return res;
}

DEV float f5f(float x, float a, float xs, float b, float xc) {
    float res = 0.0f;
    if (x > 0.0f) res = 1.0f;
    else if (x > xs) res = 1.0f - a * x * x;
    else if (x > xc) { float d = xc - x; res = b * d * d; }
    return res;
}

// block = 256 threads = 4 waves; double reduce, atomic to one of 64 slots
DEV void block_reduce_atomic(float e, double* __restrict__ slots) {
    double v = (double)e;
#pragma unroll
    for (int off = 32; off > 0; off >>= 1) v += __shfl_down(v, off, 64);
    __shared__ double red[4];
    int lane = threadIdx.x & 63;
    int wv = threadIdx.x >> 6;
    if (lane == 0) red[wv] = v;
    __syncthreads();
    if (threadIdx.x == 0) {
        double s = red[0] + red[1] + red[2] + red[3];
        atomicAdd(slots + (blockIdx.x & 63), s);
    }
}

// EXACT Round-1 frame/site computation (proven absmax 0.0)
DEV void load_particle(const float* __restrict__ pos, const float4* __restrict__ quat, int i,
                       F3& a1, F3& a2, F3& a3, F3& back, F3& stck, F3& base) {
    float4 q = quat[i];
    float n = sqrtf(q.x * q.x + q.y * q.y + q.z * q.z + q.w * q.w + 1e-12f);
    float inv = 1.0f / n;
    float w = q.x * inv, x = q.y * inv, y = q.z * inv, z = q.w * inv;
    a1 = f3(1.0f - 2.0f * (y * y + z * z), 2.0f * (x * y + w * z), 2.0f * (x * z - w * y));
    a2 = f3(2.0f * (x * y - w * z), 1.0f - 2.0f * (x * x + z * z), 2.0f * (y * z + w * x));
    a3 = f3(2.0f * (x * z + w * y), 2.0f * (y * z - w * x), 1.0f - 2.0f * (x * x + y * y));
    F3 p = f3(pos[3 * i], pos[3 * i + 1], pos[3 * i + 2]);
    back = add3(p, scl3(a1, -0.4f));
    stck = add3(p, scl3(a1, 0.34f));
    base = add3(p, scl3(a1, 0.4f));
}

// ---------------------------------------------------------------------------
// packed records: recS = 64 B/particle (one cache line):
//   s0 = (back.x, back.y, back.z, stck.x)
//   s1 = (stck.y, stck.z, base.x, base.y)
//   s2 = (base.z, a1.x,  a1.y,  a1.z)
//   s3 = (a2.x,  a2.y,  a2.z,  btype)   <- same line; loaded only on heavy path
// recB = 16 B/particle: (a3.x, a3.y, a3.z, 0)  -- heavy path + bonded only
// ---------------------------------------------------------------------------

__global__ void __launch_bounds__(256)
prep_kernel(const float* __restrict__ pos, const float4* __restrict__ quat,
            const int* __restrict__ btypes, int n,
            float4* __restrict__ recS, float4* __restrict__ recB) {
    int i = blockIdx.x * blockDim.x + threadIdx.x;
    if (i >= n) return;
    F3 a1, a2, a3, back, stck, base;
    load_particle(pos, quat, i, a1, a2, a3, back, stck, base);
    recS[4 * i + 0] = make_float4(back.x, back.y, back.z, stck.x);
    recS[4 * i + 1] = make_float4(stck.y, stck.z, base.x, base.y);
    recS[4 * i + 2] = make_float4(base.z, a1.x, a1.y, a1.z);
    recS[4 * i + 3] = make_float4(a2.x, a2.y, a2.z, __int_as_float(btypes[i]));
    recB[i] = make_float4(a3.x, a3.y, a3.z, 0.0f);
}

struct Sites { F3 back, stck, base; };
DEV Sites unpack_sites(float4 s0, float4 s1, float4 s2) {
    Sites s;
    s.back = f3(s0.x, s0.y, s0.z);
    s.stck = f3(s0.w, s1.x, s1.y);
    s.base = f3(s1.z, s1.w, s2.x);
    return s;
}

// Nonbonded: exclusions for every pair; heavy angular path inlined, gated by
// exact radial supports (~1.7% of pairs; wave-diluted cost is hidden under
// gather latency). NO list compaction, NO contended atomics.
__global__ void __launch_bounds__(256)
nb_kernel(const float4* __restrict__ recS, const float4* __restrict__ recB,
          const float* __restrict__ hbe, const int2* __restrict__ pairs,
          int n, const float* __restrict__ boxp, double* __restrict__ slots) {
    const int T = gridDim.x * blockDim.x;
    const int t = blockIdx.x * blockDim.x + threadIdx.x;
    float bx = boxp[0], by = boxp[1], bz = boxp[2];
    F3 box = f3(bx, by, bz);
    F3 ibox = f3(1.0f / bx, 1.0f / by, 1.0f / bz);

    int2 pr[2];
    bool v[2];
    float4 si0[2], si1[2], si2[2], sj0[2], sj1[2], sj2[2];
#pragma unroll
    for (int k = 0; k < 2; k++) {
        int idx = t + k * T;
        v[k] = idx < n;
        pr[k] = v[k] ? pairs[idx] : make_int2(0, 0);
    }
#pragma unroll
    for (int k = 0; k < 2; k++) {
        const float4* ri = recS + 4 * (size_t)pr[k].x;
        const float4* rj = recS + 4 * (size_t)pr[k].y;
        si0[k] = ri[0]; si1[k] = ri[1]; si2[k] = ri[2];
        sj0[k] = rj[0]; sj1[k] = rj[1]; sj2[k] = rj[2];
    }

    float e = 0.0f;
#pragma unroll
    for (int k = 0; k < 2; k++) {
        Sites si = unpack_sites(si0[k], si1[k], si2[k]);
        Sites sj = unpack_sites(sj0[k], sj1[k], sj2[k]);

        F3 dbb = mimg(sub3(sj.back, si.back), box, ibox);
        F3 dba = mimg(sub3(sj.base, si.base), box, ibox);
        F3 dm1 = mimg(sub3(sj.base, si.back), box, ibox);  // base_j - back_i
        F3 dm2 = mimg(sub3(sj.back, si.base), box, ibox);  // back_j - base_i
        F3 dst = mimg(sub3(sj.stck, si.stck), box, ibox);

        float rrbb = dot3(dbb, dbb) + 1e-12f;
        float rrb  = dot3(dba, dba) + 1e-12f;
        float rr1  = dot3(dm1, dm1) + 1e-12f;
        float rr2  = dot3(dm2, dm2) + 1e-12f;
        float rrs  = dot3(dst, dst) + 1e-12f;

        float ek = 0.0f;
        if (rrbb < 0.711879214356f * 0.711879214356f)
            ek += fexcl(sqrtf(rrbb), 0.7f, 0.675f, 892.016223343f, 0.711879214356f);
        if (rrb < 0.335388426126f * 0.335388426126f)
            ek += fexcl(sqrtf(rrb), 0.33f, 0.32f, 4119.70450017f, 0.335388426126f);
        if (rr1 < 0.52329943261f * 0.52329943261f)
            ek += fexcl(sqrtf(rr1), 0.515f, 0.5f, 2047.42812499f, 0.52329943261f);
        if (rr2 < 0.52329943261f * 0.52329943261f)
            ek += fexcl(sqrtf(rr2), 0.515f, 0.5f, 2047.42812499f, 0.52329943261f);
        e += v[k] ? ek : 0.0f;

        // heavy path: hb/crst support rb in (0.276,0.783); cxst support rcx in (0.2,0.62)
        bool active = v[k] && ((rrb > 0.276f * 0.276f && rrb < 0.783f * 0.783f) ||
                               (rrs > 0.2f * 0.2f && rrs < 0.62f * 0.62f));
        if (active) {
            int i = pr[k].x, j = pr[k].y;
            // 4th float4 of already-fetched lines + a3 records
            float4 i3 = recS[4 * (size_t)i + 3];
            float4 j3 = recS[4 * (size_t)j + 3];
            float4 b3i = recB[i], b3j = recB[j];
            F3 a1i = f3(si2[k].y, si2[k].z, si2[k].w);
            F3 a1j = f3(sj2[k].y, sj2[k].z, sj2[k].w);
            F3 a2i = f3(i3.x, i3.y, i3.z), a2j = f3(j3.x, j3.y, j3.z);
            F3 a3i = f3(b3i.x, b3i.y, b3i.z), a3j = f3(b3j.x, b3j.y, b3j.z);
            int bti = __float_as_int(i3.w), btj = __float_as_int(j3.w);

            float rb = sqrtf(rrb);
            F3 rhat = scl3(dba, 1.0f / rb);

            float t1  = acosc(-dot3(a1i, a1j));
            float t2  = acosc(-dot3(a1j, rhat));
            float t3  = acosc(dot3(a1i, rhat));
            float t4h = acosc(dot3(a3i, a3j));
            float t7  = acosc(-dot3(a3j, rhat));
            float t8  = acosc(dot3(a3i, rhat));

            float eps = hbe[bti * 4 + btj];
            float f4t7 = f4f(t7, 4.0f, HPIF, 0.45f, 17.0526f, 0.555556f);
            e += eps
               * f1f(rb, 8.0f, 0.4f, 0.88207774f, 0.34f, 0.7f, -126.2f, 0.276f, -7.87f, 0.783f)
               * f4f(t1, 1.5f, 0.0f, 0.7f, 4.16038f, 0.952381f)
               * f4f(t2, 1.5f, 0.0f, 0.7f, 4.16038f, 0.952381f)
               * f4f(t3, 1.5f, 0.0f, 0.7f, 4.16038f, 0.952381f)
               * f4f(t4h, 0.46f, PIF, 0.7f, 1.14813f, 3.0f)
               * f4t7
               * f4f(t8, 4.0f, HPIF, 0.45f, 17.0526f, 0.555556f);

            e += f2f(rb, 47.5f, 0.575f, 0.675f, 0.495f, 0.655f, -0.888f, 0.45f, -0.888f, 0.68f)
               * f4f(t1, 2.25f, 0.791592653589793f, 0.58f, 10.9032f, 0.766284f)
               * f4f(t4h, 1.5f, 0.0f, 0.7f, 4.16038f, 0.952381f)
               * (f4t7 + f4f(PIF - t7, 4.0f, HPIF, 0.45f, 17.0526f, 0.555556f));

            float rcx = sqrtf(rrs);
            F3 rchat = scl3(dst, 1.0f / rcx);
            float ct5 = acosc(dot3(a3j, rchat));
            float cphi3 = dot3(a2i, a2j);
            e += f2f(rcx, 46.0f, 0.4f, 0.6f, 0.22f, 0.58f, -0.7f, 0.2f, -0.7f, 0.62f)
               * f4f(t1, 2.0f, 2.592f, 0.65f, 10.9032f, 0.766284f)
               * f4f(t4h, 1.3f, 0.0f, 0.8f, 6.4f, 0.961538f)
               * f4f(ct5, 0.9f, 0.0f, 0.95f, 3.9f, 1.16959f)
               * f5f(cphi3, 2.0f, -0.65f, 10.9032f, -0.769231f);
        }
    }
    block_reduce_atomic(e, slots);
}

// bonded from packed records (sites are exact reference fp32 values)
__global__ void __launch_bounds__(256)
bonded_packed_kernel(const float4* __restrict__ recS, const float4* __restrict__ recB,
                     const float* __restrict__ seps, const float* __restrict__ boxp,
                     const int2* __restrict__ pairs, int n, double* __restrict__ slots) {
    int t = blockIdx.x * blockDim.x + threadIdx.x;
    float e = 0.0f;
    if (t < n) {
        float bx = boxp[0], by = boxp[1], bz = boxp[2];
        F3 box = f3(bx, by, bz);
        F3 ibox = f3(1.0f / bx, 1.0f / by, 1.0f / bz);
        int2 p = pairs[t];
        int i = p.x, j = p.y;
        float4 i0 = recS[4 * (size_t)i], i1 = recS[4 * (size_t)i + 1],
               i2 = recS[4 * (size_t)i + 2], i3 = recS[4 * (size_t)i + 3];
        float4 j0 = recS[4 * (size_t)j], j1 = recS[4 * (size_t)j + 1],
               j2 = recS[4 * (size_t)j + 2], j3 = recS[4 * (size_t)j + 3];
        float4 b3i = recB[i], b3j = recB[j];
        Sites si = unpack_sites(i0, i1, i2);
        Sites sj = unpack_sites(j0, j1, j2);
        F3 a2i = f3(i3.x, i3.y, i3.z), a2j = f3(j3.x, j3.y, j3.z);
        F3 a3i = f3(b3i.x, b3i.y, b3i.z), a3j = f3(b3j.x, b3j.y, b3j.z);

        // FENE
        F3 dbb = mimg(sub3(sj.back, si.back), box, ibox);
        float rbb = norm3(dbb);
        float u = (rbb - 0.7525f) * 4.0f;
        float arg = u * u;
        arg = fminf(fmaxf(arg, 0.0f), 1.0f - 1e-6f);
        e += -log1pf(-arg);  // -0.5 * FENE_EPS(2) * log1p

        // bonded exclusions
        e += fexcl(norm3(mimg(sub3(sj.base, si.base), box, ibox)), 0.33f, 0.32f, 4119.70450017f, 0.335388426126f);
        e += fexcl(norm3(mimg(sub3(sj.base, si.back), box, ibox)), 0.515f, 0.5f, 2047.42812499f, 0.52329943261f);
        e += fexcl(norm3(mimg(sub3(sj.back, si.base), box, ibox)), 0.515f, 0.5f, 2047.42812499f, 0.52329943261f);

        // stacking
        F3 ds = mimg(sub3(sj.stck, si.stck), box, ibox);
        float rs = norm3(ds);
        F3 rhat = scl3(ds, 1.0f / rs);
        float t4 = acosc(dot3(a3i, a3j));
        float t5 = acosc(dot3(a3j, rhat));
        float t6 = acosc(-dot3(a3i, rhat));
        F3 rbhat = scl3(dbb, 1.0f / rbb);
        float cphi1 = dot3(a2i, rbhat);
        float cphi2 = dot3(a2j, rbhat);
        e += seps[t]
           * f1f(rs, 6.0f, 0.4f, 0.90290461f, 0.32f, 0.75f, -0.68f, 0.26f, -12.6f, 0.8f)
           * f4f(t4, 1.3f, 0.0f, 0.8f, 6.4f, 0.961538f)
           * f4f(t5, 0.9f, 0.0f, 0.95f, 3.9f, 1.16959f)
           * f4f(t6, 0.9f, 0.0f, 0.95f, 3.9f, 1.16959f)
           * f5f(cphi1, 2.0f, -0.65f, 10.9032f, -0.769231f)
           * f5f(cphi2, 2.0f, -0.65f, 10.9032f, -0.769231f);
    }
    block_reduce_atomic(e, slots);
}

__global__ void finalize_kernel(const double* __restrict__ slots, float* __restrict__ out) {
    double v = slots[threadIdx.x];
#pragma unroll
    for (int off = 32; off > 0; off >>= 1) v += __shfl_down(v, off, 64);
    if (threadIdx.x == 0) out[0] = (float)v;
}

// ---------------------------------------------------------------------------
// mono fallback (Round-1 proven path), used only if ws_size too small
// ---------------------------------------------------------------------------

__global__ void __launch_bounds__(256)
mono_bonded_kernel(const float* __restrict__ pos, const float4* __restrict__ quat,
                   const float* __restrict__ seps, const float* __restrict__ boxp,
                   const int2* __restrict__ pairs, int n, double* __restrict__ slots) {
    int t = blockIdx.x * blockDim.x + threadIdx.x;
    float e = 0.0f;
    if (t < n) {
        float bx = boxp[0], by = boxp[1], bz = boxp[2];
        F3 box = f3(bx, by, bz);
        F3 ibox = f3(1.0f / bx, 1.0f / by, 1.0f / bz);
        int2 p = pairs[t];
        int i = p.x, j = p.y;
        F3 a1i, a2i, a3i, backi, stcki, basei;
        F3 a1j, a2j, a3j, backj, stckj, basej;
        load_particle(pos, quat, i, a1i, a2i, a3i, backi, stcki, basei);
        load_particle(pos, quat, j, a1j, a2j, a3j, backj, stckj, basej);
        F3 dbb = mimg(sub3(backj, backi), box, ibox);
        float rbb = norm3(dbb);
        float u = (rbb - 0.7525f) * 4.0f;
        float arg = u * u;
        arg = fminf(fmaxf(arg, 0.0f), 1.0f - 1e-6f);
        e += -log1pf(-arg);
        e += fexcl(norm3(mimg(sub3(basej, basei), box, ibox)), 0.33f, 0.32f, 4119.70450017f, 0.335388426126f);
        e += fexcl(norm3(mimg(sub3(basej, backi), box, ibox)), 0.515f, 0.5f, 2047.42812499f, 0.52329943261f);
        e += fexcl(norm3(mimg(sub3(backj, basei), box, ibox)), 0.515f, 0.5f, 2047.42812499f, 0.52329943261f);
        F3 ds = mimg(sub3(stckj, stcki), box, ibox);
        float rs = norm3(ds);
        F3 rhat = scl3(ds, 1.0f / rs);
        float t4 = acosc(dot3(a3i, a3j));
        float t5 = acosc(dot3(a3j, rhat));
        float t6 = acosc(-dot3(a3i, rhat));
        F3 rbhat = scl3(dbb, 1.0f / rbb);
        float cphi1 = dot3(a2i, rbhat);
        float cphi2 = dot3(a2j, rbhat);
        e += seps[t]
           * f1f(rs, 6.0f, 0.4f, 0.90290461f, 0.32f, 0.75f, -0.68f, 0.26f, -12.6f, 0.8f)
           * f4f(t4, 1.3f, 0.0f, 0.8f, 6.4f, 0.961538f)
           * f4f(t5, 0.9f, 0.0f, 0.95f, 3.9f, 1.16959f)
           * f4f(t6, 0.9f, 0.0f, 0.95f, 3.9f, 1.16959f)
           * f5f(cphi1, 2.0f, -0.65f, 10.9032f, -0.769231f)
           * f5f(cphi2, 2.0f, -0.65f, 10.9032f, -0.769231f);
    }
    block_reduce_atomic(e, slots);
}

__global__ void __launch_bounds__(256)
mono_nonbonded_kernel(const float* __restrict__ pos, const float4* __restrict__ quat,
                      const float* __restrict__ hbe, const float* __restrict__ boxp,
                      const int2* __restrict__ pairs, const int* __restrict__ btypes,
                      int n, double* __restrict__ slots) {
    int t = blockIdx.x * blockDim.x + threadIdx.x;
    float e = 0.0f;
    if (t < n) {
        float bx = boxp[0], by = boxp[1], bz = boxp[2];
        F3 box = f3(bx, by, bz);
        F3 ibox = f3(1.0f / bx, 1.0f / by, 1.0f / bz);
        int2 p = pairs[t];
        int i = p.x, j = p.y;
        F3 a1i, a2i, a3i, backi, stcki, basei;
        F3 a1j, a2j, a3j, backj, stckj, basej;
        load_particle(pos, quat, i, a1i, a2i, a3i, backi, stcki, basei);
        load_particle(pos, quat, j, a1j, a2j, a3j, backj, stckj, basej);
        e += fexcl(norm3(mimg(sub3(backj, backi), box, ibox)), 0.7f, 0.675f, 892.016223343f, 0.711879214356f);
        F3 dbase = mimg(sub3(basej, basei), box, ibox);
        float rb = norm3(dbase);
        e += fexcl(rb, 0.33f, 0.32f, 4119.70450017f, 0.335388426126f);
        e += fexcl(norm3(mimg(sub3(basej, backi), box, ibox)), 0.515f, 0.5f, 2047.42812499f, 0.52329943261f);
        e += fexcl(norm3(mimg(sub3(backj, basei), box, ibox)), 0.515f, 0.5f, 2047.42812499f, 0.52329943261f);
        F3 rhat = scl3(dbase, 1.0f / rb);
        float t1  = acosc(-dot3(a1i, a1j));
        float t2  = acosc(-dot3(a1j, rhat));
        float t3  = acosc(dot3(a1i, rhat));
        float t4h = acosc(dot3(a3i, a3j));
        float t7  = acosc(-dot3(a3j, rhat));
        float t8  = acosc(dot3(a3i, rhat));
        int bti = btypes[i], btj = btypes[j];
        float eps = hbe[bti * 4 + btj];
        float f4t7 = f4f(t7, 4.0f, HPIF, 0.45f, 17.0526f, 0.555556f);
        e += eps
           * f1f(rb, 8.0f, 0.4f, 0.88207774f, 0.34f, 0.7f, -126.2f, 0.276f, -7.87f, 0.783f)
           * f4f(t1, 1.5f, 0.0f, 0.7f, 4.16038f, 0.952381f)
           * f4f(t2, 1.5f, 0.0f, 0.7f, 4.16038f, 0.952381f)
           * f4f(t3, 1.5f, 0.0f, 0.7f, 4.16038f, 0.952381f)
           * f4f(t4h, 0.46f, PIF, 0.7f, 1.14813f, 3.0f)
           * f4t7
           * f4f(t8, 4.0f, HPIF, 0.45f, 17.0526f, 0.555556f);
        e += f2f(rb, 47.5f, 0.575f, 0.675f, 0.495f, 0.655f, -0.888f, 0.45f, -0.888f, 0.68f)
           * f4f(t1, 2.25f, 0.791592653589793f, 0.58f, 10.9032f, 0.766284f)
           * f4f(t4h, 1.5f, 0.0f, 0.7f, 4.16038f, 0.952381f)
           * (f4t7 + f4f(PIF - t7, 4.0f, HPIF, 0.45f, 17.0526f, 0.555556f));
        F3 dc = mimg(sub3(stckj, stcki), box, ibox);
        float rcx = norm3(dc);
        F3 rchat = scl3(dc, 1.0f / rcx);
        float ct5 = acosc(dot3(a3j, rchat));
        float cphi3 = dot3(a2i, a2j);
        e += f2f(rcx, 46.0f, 0.4f, 0.6f, 0.22f, 0.58f, -0.7f, 0.2f, -0.7f, 0.62f)
           * f4f(t1, 2.0f, 2.592f, 0.65f, 10.9032f, 0.766284f)
           * f4f(t4h, 1.3f, 0.0f, 0.8f, 6.4f, 0.961538f)
           * f4f(ct5, 0.9f, 0.0f, 0.95f, 3.9f, 1.16959f)
           * f5f(cphi3, 2.0f, -0.65f, 10.9032f, -0.769231f);
    }
    block_reduce_atomic(e, slots);
}

extern "C" void kernel_launch(void* const* d_in, const int* in_sizes, int n_in,
                              void* d_out, int out_size, void* d_ws, size_t ws_size,
                              hipStream_t stream) {
    const float*  pos  = (const float*)d_in[0];
    const float4* quat = (const float4*)d_in[1];
    const float*  seps = (const float*)d_in[2];
    const float*  hbe  = (const float*)d_in[3];
    const float*  boxp = (const float*)d_in[4];
    const int2*   bp   = (const int2*)d_in[5];
    const int2*   nbp  = (const int2*)d_in[6];
    const int*    bt   = (const int*)d_in[7];

    int N    = in_sizes[0] / 3;
    int n_b  = in_sizes[5] / 2;
    int n_nb = in_sizes[6] / 2;

    char* ws = (char*)d_ws;
    // layout: [0,512) slots, [1024,..) recS (64B/p), recB (16B/p)
    size_t off_recS = 1024;
    size_t off_recB = off_recS + (size_t)N * 64;
    size_t required = off_recB + (size_t)N * 16;

    if (ws_size >= required) {
        double* slots = (double*)ws;
        float4* recS  = (float4*)(ws + off_recS);
        float4* recB  = (float4*)(ws + off_recB);
        hipMemsetAsync(ws, 0, 512, stream);
        prep_kernel<<<(N + 255) / 256, 256, 0, stream>>>(pos, quat, bt, N, recS, recB);
        bonded_packed_kernel<<<(n_b + 255) / 256, 256, 0, stream>>>(recS, recB, seps, boxp, bp, n_b, slots);
        int nb_threads = (n_nb + 1) / 2;
        int nb_blocks = (nb_threads + 255) / 256;
        nb_kernel<<<nb_blocks, 256, 0, stream>>>(recS, recB, hbe, nbp, n_nb, boxp, slots);
        finalize_kernel<<<1, 64, 0, stream>>>(slots, (float*)d_out);
    } else {
        double* slots = (double*)ws;
        hipMemsetAsync(ws, 0, 512, stream);
        mono_bonded_kernel<<<(n_b + 255) / 256, 256, 0, stream>>>(pos, quat, seps, boxp, bp, n_b, slots);
        mono_nonbonded_kernel<<<(n_nb + 255) / 256, 256, 0, stream>>>(pos, quat, hbe, boxp, nbp, bt, n_nb, slots);
        finalize_kernel<<<1, 64, 0, stream>>>(slots, (float*)d_out);
    }
}